// Round 4
// baseline (457.689 us; speedup 1.0000x reference)
//
#include <hip/hip_runtime.h>

#define D 64
#define SCAN_CHUNK 1024   // elements per scan1 block (256 thr x 4)

__device__ __forceinline__ unsigned int bf16r(float f) {
    unsigned int u = __float_as_uint(f);
    return (u + 0x7fffu + ((u >> 16) & 1u)) >> 16;   // RNE truncate to bf16
}

__device__ __forceinline__ void bf2f4(uint2 u, float& f0, float& f1, float& f2, float& f3) {
    f0 = __uint_as_float(u.x << 16);
    f1 = __uint_as_float(u.x & 0xffff0000u);
    f2 = __uint_as_float(u.y << 16);
    f3 = __uint_as_float(u.y & 0xffff0000u);
}

// ---------------- f32 -> bf16 row conversion (8 elems/thread) --------------
__global__ __launch_bounds__(256) void cvt_kernel(
    const float* __restrict__ in, unsigned short* __restrict__ out, int n8)
{
    int t = blockIdx.x * 256 + threadIdx.x;
    if (t >= n8) return;
    const float4* p = reinterpret_cast<const float4*>(in) + (size_t)t * 2;
    float4 v0 = p[0], v1 = p[1];
    uint4 o;
    o.x = bf16r(v0.x) | (bf16r(v0.y) << 16);
    o.y = bf16r(v0.z) | (bf16r(v0.w) << 16);
    o.z = bf16r(v1.x) | (bf16r(v1.y) << 16);
    o.w = bf16r(v1.z) | (bf16r(v1.w) << 16);
    reinterpret_cast<uint4*>(out)[t] = o;
}

// ---------------- tap0: y[row][j] = sum_i x[row][i]*W[j][i] + b[j] ---------
__global__ __launch_bounds__(256) void tap_kernel(
    const float* __restrict__ xin, const float* __restrict__ W,
    const float* __restrict__ b, float* __restrict__ y,
    int n_nodes, int first)
{
    __shared__ float Wt[D * (D + 1)];
    __shared__ float bs[D];
    __shared__ float xs[4][D];

    int tid = threadIdx.x;
    for (int t = tid; t < D * D; t += 256) {
        int j = t >> 6, i = t & 63;
        Wt[i * (D + 1) + j] = W[t];
    }
    if (tid < D) bs[tid] = b[tid];

    int rl = tid >> 6;
    int j  = tid & 63;
    int row = blockIdx.x * 4 + rl;
    if (row < n_nodes) xs[rl][j] = xin[(size_t)row * D + j];
    __syncthreads();

    if (row >= n_nodes) return;

    float acc = bs[j];
    #pragma unroll 8
    for (int i = 0; i < D; ++i)
        acc = fmaf(xs[rl][i], Wt[i * (D + 1) + j], acc);

    float* yp = y + (size_t)row * D + j;
    *yp = first ? acc : (*yp + acc);
}

// ---------------- CSR build ------------------------------------------------
__global__ __launch_bounds__(256) void hist_loc_kernel(
    const int* __restrict__ dst, int* __restrict__ counts,
    int* __restrict__ loc, int n_edges)
{
    int t = blockIdx.x * 256 + threadIdx.x;
    int e4 = t * 4;
    if (e4 + 4 <= n_edges) {
        int4 d = *reinterpret_cast<const int4*>(dst + e4);
        int4 l;
        l.x = atomicAdd(&counts[d.x], 1);
        l.y = atomicAdd(&counts[d.y], 1);
        l.z = atomicAdd(&counts[d.z], 1);
        l.w = atomicAdd(&counts[d.w], 1);
        *reinterpret_cast<int4*>(loc + e4) = l;
    } else {
        for (int e = e4; e < n_edges; ++e)
            loc[e] = atomicAdd(&counts[dst[e]], 1);
    }
}

__global__ __launch_bounds__(256) void scan1_kernel(
    const int* __restrict__ counts, int* __restrict__ excl,
    int* __restrict__ bsum, int n)
{
    __shared__ int lds[256];
    int tid = threadIdx.x;
    int base = blockIdx.x * SCAN_CHUNK + tid * 4;
    int c0 = 0, c1 = 0, c2 = 0, c3 = 0;
    if (base + 3 < n) {
        int4 v = *reinterpret_cast<const int4*>(counts + base);
        c0 = v.x; c1 = v.y; c2 = v.z; c3 = v.w;
    } else {
        if (base + 0 < n) c0 = counts[base + 0];
        if (base + 1 < n) c1 = counts[base + 1];
        if (base + 2 < n) c2 = counts[base + 2];
        if (base + 3 < n) c3 = counts[base + 3];
    }
    int s = c0 + c1 + c2 + c3;
    lds[tid] = s;
    __syncthreads();
    for (int off = 1; off < 256; off <<= 1) {
        int v = (tid >= off) ? lds[tid - off] : 0;
        __syncthreads();
        lds[tid] += v;
        __syncthreads();
    }
    int incl = lds[tid];
    int ex = incl - s;
    if (tid == 255) bsum[blockIdx.x] = incl;
    if (base + 0 < n) excl[base + 0] = ex;
    if (base + 1 < n) excl[base + 1] = ex + c0;
    if (base + 2 < n) excl[base + 2] = ex + c0 + c1;
    if (base + 3 < n) excl[base + 3] = ex + c0 + c1 + c2;
}

__global__ __launch_bounds__(64) void scan2_kernel(int* __restrict__ bsum, int nb)
{
    int lane = threadIdx.x;
    int v = (lane < nb) ? bsum[lane] : 0;
    int orig = v;
    for (int off = 1; off < 64; off <<= 1) {
        int t = __shfl_up(v, off);
        if (lane >= off) v += t;
    }
    if (lane < nb) bsum[lane] = v - orig;
}

__global__ __launch_bounds__(256) void scan3_kernel(
    const int* __restrict__ excl, const int* __restrict__ bsum,
    int* __restrict__ rp, int n, int n_edges)
{
    int i = blockIdx.x * 256 + threadIdx.x;
    if (i < n) rp[i] = excl[i] + bsum[i / SCAN_CHUNK];
    if (i == 0) rp[n] = n_edges;
}

__global__ __launch_bounds__(256) void fill2_kernel(
    const int* __restrict__ src, const int* __restrict__ dst,
    const int* __restrict__ rp, const int* __restrict__ loc,
    int* __restrict__ csr, int n_edges)
{
    int t = blockIdx.x * 256 + threadIdx.x;
    int e4 = t * 4;
    if (e4 + 4 <= n_edges) {
        int4 d = *reinterpret_cast<const int4*>(dst + e4);
        int4 s = *reinterpret_cast<const int4*>(src + e4);
        int4 l = *reinterpret_cast<const int4*>(loc + e4);
        csr[rp[d.x] + l.x] = s.x;
        csr[rp[d.y] + l.y] = s.y;
        csr[rp[d.z] + l.z] = s.z;
        csr[rp[d.w] + l.w] = s.w;
    } else {
        for (int e = e4; e < n_edges; ++e)
            csr[rp[dst[e]] + loc[e]] = src[e];
    }
}

// ------- fused shift+tap (bf16 gather, f32 accumulate, reg-W matvec) -------
// agg = S xin ; y += agg @ Wk^T + bk ; optionally xaggb = bf16(agg)
__global__ __launch_bounds__(512, 2) void pull_tap_kernel(
    const unsigned short* __restrict__ xin,   // bf16 rows [n][64]
    unsigned short* __restrict__ xaggb,       // bf16 agg rows out
    float* __restrict__ y,
    const int* __restrict__ rp, const int* __restrict__ csr,
    const float* __restrict__ Wk, const float* __restrict__ bk,
    int n_nodes, int write_agg)
{
    __shared__ float4 xsh[8][16];   // per-wave agg staging (8 waves/block)

    int tid  = threadIdx.x;
    int wv   = tid >> 6;
    int lane = tid & 63;
    int grp  = lane >> 4;   // which of 4 edges in a quad
    int cl   = lane & 15;   // 8-byte chunk of the 128B bf16 row

    // W row into registers: wr[i] = W[lane][i]  (L1/L2-cached, 16KB shared by all)
    float wr[64];
    {
        const float4* Wp = reinterpret_cast<const float4*>(Wk) + lane * 16;
        #pragma unroll
        for (int ib = 0; ib < 16; ++ib) {
            float4 w4 = Wp[ib];
            wr[4*ib+0] = w4.x; wr[4*ib+1] = w4.y;
            wr[4*ib+2] = w4.z; wr[4*ib+3] = w4.w;
        }
    }
    float bias = bk[lane];

    int node = blockIdx.x * 8 + wv;
    if (node >= n_nodes) return;

    int beg = rp[node], end = rp[node + 1];

    float a0x=0,a0y=0,a0z=0,a0w=0;
    float a1x=0,a1y=0,a1z=0,a1w=0;
    float a2x=0,a2y=0,a2z=0,a2w=0;
    float a3x=0,a3y=0,a3z=0,a3w=0;
    float f0,f1,f2,f3;

    for (int base = beg; base < end; base += 64) {
        int m = end - base; if (m > 64) m = 64;
        int idx = (lane < m) ? csr[base + lane] : 0;
        int i = 0;
        for (; i + 16 <= m; i += 16) {      // 16 rows in flight per wave
            int s0 = __shfl(idx, i + grp);
            int s1 = __shfl(idx, i + 4 + grp);
            int s2 = __shfl(idx, i + 8 + grp);
            int s3 = __shfl(idx, i + 12 + grp);
            uint2 u0 = reinterpret_cast<const uint2*>(xin + (size_t)s0 * D)[cl];
            uint2 u1 = reinterpret_cast<const uint2*>(xin + (size_t)s1 * D)[cl];
            uint2 u2 = reinterpret_cast<const uint2*>(xin + (size_t)s2 * D)[cl];
            uint2 u3 = reinterpret_cast<const uint2*>(xin + (size_t)s3 * D)[cl];
            bf2f4(u0, f0,f1,f2,f3); a0x+=f0; a0y+=f1; a0z+=f2; a0w+=f3;
            bf2f4(u1, f0,f1,f2,f3); a1x+=f0; a1y+=f1; a1z+=f2; a1w+=f3;
            bf2f4(u2, f0,f1,f2,f3); a2x+=f0; a2y+=f1; a2z+=f2; a2w+=f3;
            bf2f4(u3, f0,f1,f2,f3); a3x+=f0; a3y+=f1; a3z+=f2; a3w+=f3;
        }
        for (; i + 4 <= m; i += 4) {
            int s = __shfl(idx, i + grp);
            uint2 u = reinterpret_cast<const uint2*>(xin + (size_t)s * D)[cl];
            bf2f4(u, f0,f1,f2,f3); a0x+=f0; a0y+=f1; a0z+=f2; a0w+=f3;
        }
        if (i < m) {
            int t = i + grp;
            int s = __shfl(idx, t < m ? t : 0);
            if (t < m) {
                uint2 u = reinterpret_cast<const uint2*>(xin + (size_t)s * D)[cl];
                bf2f4(u, f0,f1,f2,f3); a0x+=f0; a0y+=f1; a0z+=f2; a0w+=f3;
            }
        }
    }

    // combine 4 accumulators, then cross-group (xor 16, 32) reduce
    float rx = (a0x+a1x)+(a2x+a3x);
    float ry = (a0y+a1y)+(a2y+a3y);
    float rz = (a0z+a1z)+(a2z+a3z);
    float rw = (a0w+a1w)+(a2w+a3w);
    rx += __shfl_xor(rx, 16); ry += __shfl_xor(ry, 16);
    rz += __shfl_xor(rz, 16); rw += __shfl_xor(rw, 16);
    rx += __shfl_xor(rx, 32); ry += __shfl_xor(ry, 32);
    rz += __shfl_xor(rz, 32); rw += __shfl_xor(rw, 32);

    // write next-stage bf16 rows (grp0: 16 lanes x 8B = 128B coalesced)
    if (write_agg && grp == 0) {
        uint2 ob;
        ob.x = bf16r(rx) | (bf16r(ry) << 16);
        ob.y = bf16r(rz) | (bf16r(rw) << 16);
        reinterpret_cast<uint2*>(xaggb + (size_t)node * D)[cl] = ob;
    }

    // stage f32 agg for wave-wide broadcast (1 ds_write_b128 from grp0)
    if (grp == 0) xsh[wv][cl] = make_float4(rx, ry, rz, rw);
    asm volatile("s_waitcnt lgkmcnt(0)" ::: "memory");
    __builtin_amdgcn_sched_barrier(0);

    // matvec: y[node][lane] += sum_i agg[i]*W[lane][i] + b[lane]
    float o0 = bias, o1 = 0.f, o2 = 0.f, o3 = 0.f;
    #pragma unroll
    for (int ib = 0; ib < 16; ++ib) {
        float4 xv = xsh[wv][ib];              // same-addr broadcast read
        o0 = fmaf(xv.x, wr[4*ib+0], o0);
        o1 = fmaf(xv.y, wr[4*ib+1], o1);
        o2 = fmaf(xv.z, wr[4*ib+2], o2);
        o3 = fmaf(xv.w, wr[4*ib+3], o3);
    }
    y[(size_t)node * D + lane] += (o0 + o1) + (o2 + o3);
}

// ---------------- fallback (atomic push) if ws too small -------------------
__global__ __launch_bounds__(256) void scatter_kernel(
    const float* __restrict__ xin, float* __restrict__ xout,
    const int* __restrict__ src, const int* __restrict__ dst, int n_edges)
{
    int t = blockIdx.x * blockDim.x + threadIdx.x;
    int e = t >> 4;
    if (e >= n_edges) return;
    int c = (t & 15) * 4;
    int s = src[e];
    int d = dst[e];
    const float4 v = *reinterpret_cast<const float4*>(xin + (size_t)s * D + c);
    float* o = xout + (size_t)d * D + c;
    atomicAdd(o + 0, v.x);
    atomicAdd(o + 1, v.y);
    atomicAdd(o + 2, v.z);
    atomicAdd(o + 3, v.w);
}

extern "C" void kernel_launch(void* const* d_in, const int* in_sizes, int n_in,
                              void* d_out, int out_size, void* d_ws, size_t ws_size,
                              hipStream_t stream) {
    const float* x  = (const float*)d_in[0];
    const int*   ei = (const int*)d_in[1];
    const float* W  = (const float*)d_in[2];
    const float* b  = (const float*)d_in[3];
    float* y = (float*)d_out;

    int n_nodes = in_sizes[0] / D;   // 50000
    int n_edges = in_sizes[1] / 2;   // 800000
    const int* src = ei;
    const int* dst = ei + n_edges;

    int n_pad = ((n_nodes + SCAN_CHUNK - 1) / SCAN_CHUNK) * SCAN_CHUNK; // 50176
    int nblk  = n_pad / SCAN_CHUNK;                                      // 49

    size_t bufElems = (size_t)n_nodes * D;          // 3.2M
    unsigned short* xb = (unsigned short*)d_ws;     // bf16 x
    unsigned short* Ab = xb + bufElems;             // bf16 agg ping
    unsigned short* Bb = Ab + bufElems;             // bf16 agg pong
    int* counts = (int*)(Bb + bufElems);
    int* excl   = counts + n_pad;
    int* rp     = excl + n_pad;        // n_nodes+1 used
    int* bsum   = rp + n_pad;          // 64
    int* loc    = bsum + 64;           // n_edges
    int* csr    = loc + n_edges;       // n_edges

    size_t needed = (char*)(csr + n_edges) - (char*)d_ws;

    dim3 tb(256);
    dim3 tg((n_nodes + 3) / 4);
    int e4grid = (n_edges / 4 + 255) / 256;
    int ngrid  = (n_nodes + 255) / 256;
    int n8     = (int)(bufElems / 8);
    int cgrid  = (n8 + 255) / 256;
    int pgrid  = (n_nodes + 7) / 8;    // 512-thread blocks, 8 nodes each

    if (needed <= ws_size) {
        // ---- bf16 copy of x + CSR build ----
        cvt_kernel<<<cgrid, tb, 0, stream>>>(x, xb, n8);
        hipMemsetAsync(counts, 0, (size_t)n_pad * sizeof(int), stream);
        hist_loc_kernel<<<e4grid, tb, 0, stream>>>(dst, counts, loc, n_edges);
        scan1_kernel<<<nblk, tb, 0, stream>>>(counts, excl, bsum, n_nodes);
        scan2_kernel<<<1, 64, 0, stream>>>(bsum, nblk);
        scan3_kernel<<<ngrid, tb, 0, stream>>>(excl, bsum, rp, n_nodes, n_edges);
        fill2_kernel<<<e4grid, tb, 0, stream>>>(src, dst, rp, loc, csr, n_edges);

        // ---- tap 0 (f32) + fused bf16 shift/tap chain ----
        tap_kernel<<<tg, tb, 0, stream>>>(x, W, b, y, n_nodes, 1);
        pull_tap_kernel<<<pgrid, 512, 0, stream>>>(xb, Ab, y, rp, csr,
                                                   W + 1 * D * D, b + 1 * D, n_nodes, 1);
        pull_tap_kernel<<<pgrid, 512, 0, stream>>>(Ab, Bb, y, rp, csr,
                                                   W + 2 * D * D, b + 2 * D, n_nodes, 1);
        pull_tap_kernel<<<pgrid, 512, 0, stream>>>(Bb, Ab, y, rp, csr,
                                                   W + 3 * D * D, b + 3 * D, n_nodes, 0);
    } else {
        // ---- fallback: atomic push path (f32) ----
        float* A = (float*)d_ws;
        float* B = A + bufElems;
        size_t bufBytes = bufElems * sizeof(float);
        int sgrid = (n_edges * 16 + 255) / 256;
        hipMemsetAsync(A, 0, bufBytes, stream);
        hipMemsetAsync(B, 0, bufBytes, stream);
        tap_kernel<<<tg, tb, 0, stream>>>(x, W, b, y, n_nodes, 1);
        scatter_kernel<<<sgrid, tb, 0, stream>>>(x, A, src, dst, n_edges);
        tap_kernel<<<tg, tb, 0, stream>>>(A, W + D * D, b + D, y, n_nodes, 0);
        scatter_kernel<<<sgrid, tb, 0, stream>>>(A, B, src, dst, n_edges);
        hipMemsetAsync(A, 0, bufBytes, stream);
        tap_kernel<<<tg, tb, 0, stream>>>(B, W + 2 * D * D, b + 2 * D, y, n_nodes, 0);
        scatter_kernel<<<sgrid, tb, 0, stream>>>(B, A, src, dst, n_edges);
        tap_kernel<<<tg, tb, 0, stream>>>(A, W + 3 * D * D, b + 3 * D, y, n_nodes, 0);
    }
}

// Round 5
// 235.138 us; speedup vs baseline: 1.9465x; 1.9465x over previous
//
#include <hip/hip_runtime.h>

#define D 64
#define SCAN_CHUNK 1024   // elements per scan1 block (256 thr x 4)

__device__ __forceinline__ unsigned int bf16r(float f) {
    unsigned int u = __float_as_uint(f);
    return (u + 0x7fffu + ((u >> 16) & 1u)) >> 16;   // RNE to bf16
}

// ---------------- f32 -> bf16 row conversion (8 elems/thread) --------------
__global__ __launch_bounds__(256) void cvt_kernel(
    const float* __restrict__ in, unsigned short* __restrict__ out, int n8)
{
    int t = blockIdx.x * 256 + threadIdx.x;
    if (t >= n8) return;
    const float4* p = reinterpret_cast<const float4*>(in) + (size_t)t * 2;
    float4 v0 = p[0], v1 = p[1];
    uint4 o;
    o.x = bf16r(v0.x) | (bf16r(v0.y) << 16);
    o.y = bf16r(v0.z) | (bf16r(v0.w) << 16);
    o.z = bf16r(v1.x) | (bf16r(v1.y) << 16);
    o.w = bf16r(v1.z) | (bf16r(v1.w) << 16);
    reinterpret_cast<uint4*>(out)[t] = o;
}

// ---------------- tap0 (f32 in): y[row][j] = sum_i x[row][i]*W[j][i]+b[j] --
__global__ __launch_bounds__(256) void tap_kernel(
    const float* __restrict__ xin, const float* __restrict__ W,
    const float* __restrict__ b, float* __restrict__ y,
    int n_nodes, int first)
{
    __shared__ float Wt[D * (D + 1)];
    __shared__ float bs[D];
    __shared__ float xs[4][D];

    int tid = threadIdx.x;
    for (int t = tid; t < D * D; t += 256) {
        int j = t >> 6, i = t & 63;
        Wt[i * (D + 1) + j] = W[t];
    }
    if (tid < D) bs[tid] = b[tid];

    int rl = tid >> 6;
    int j  = tid & 63;
    int row = blockIdx.x * 4 + rl;
    if (row < n_nodes) xs[rl][j] = xin[(size_t)row * D + j];
    __syncthreads();

    if (row >= n_nodes) return;

    float acc = bs[j];
    #pragma unroll 8
    for (int i = 0; i < D; ++i)
        acc = fmaf(xs[rl][i], Wt[i * (D + 1) + j], acc);

    float* yp = y + (size_t)row * D + j;
    *yp = first ? acc : (*yp + acc);
}

// ---------------- tap (bf16 in): y[row][j] += sum_i xb[row][i]*W[j][i]+b[j]
__global__ __launch_bounds__(256) void tap_bf16_kernel(
    const unsigned short* __restrict__ xin, const float* __restrict__ W,
    const float* __restrict__ b, float* __restrict__ y, int n_nodes)
{
    __shared__ float Wt[D * (D + 1)];
    __shared__ float bs[D];
    __shared__ float xs[4][D];

    int tid = threadIdx.x;
    for (int t = tid; t < D * D; t += 256) {
        int j = t >> 6, i = t & 63;
        Wt[i * (D + 1) + j] = W[t];
    }
    if (tid < D) bs[tid] = b[tid];

    int rl = tid >> 6;
    int lane = tid & 63;
    int row = blockIdx.x * 4 + rl;
    if (row < n_nodes && lane < 32) {
        unsigned int u = reinterpret_cast<const unsigned int*>(xin + (size_t)row * D)[lane];
        xs[rl][2 * lane]     = __uint_as_float(u << 16);
        xs[rl][2 * lane + 1] = __uint_as_float(u & 0xffff0000u);
    }
    __syncthreads();

    if (row >= n_nodes) return;

    float acc = bs[lane];
    #pragma unroll 8
    for (int i = 0; i < D; ++i)
        acc = fmaf(xs[rl][i], Wt[i * (D + 1) + lane], acc);

    y[(size_t)row * D + lane] += acc;
}

// ---------------- CSR build ------------------------------------------------
__global__ __launch_bounds__(256) void hist_loc_kernel(
    const int* __restrict__ dst, int* __restrict__ counts,
    int* __restrict__ loc, int n_edges)
{
    int t = blockIdx.x * 256 + threadIdx.x;
    int e4 = t * 4;
    if (e4 + 4 <= n_edges) {
        int4 d = *reinterpret_cast<const int4*>(dst + e4);
        int4 l;
        l.x = atomicAdd(&counts[d.x], 1);
        l.y = atomicAdd(&counts[d.y], 1);
        l.z = atomicAdd(&counts[d.z], 1);
        l.w = atomicAdd(&counts[d.w], 1);
        *reinterpret_cast<int4*>(loc + e4) = l;
    } else {
        for (int e = e4; e < n_edges; ++e)
            loc[e] = atomicAdd(&counts[dst[e]], 1);
    }
}

__global__ __launch_bounds__(256) void scan1_kernel(
    const int* __restrict__ counts, int* __restrict__ excl,
    int* __restrict__ bsum, int n)
{
    __shared__ int lds[256];
    int tid = threadIdx.x;
    int base = blockIdx.x * SCAN_CHUNK + tid * 4;
    int c0 = 0, c1 = 0, c2 = 0, c3 = 0;
    if (base + 3 < n) {
        int4 v = *reinterpret_cast<const int4*>(counts + base);
        c0 = v.x; c1 = v.y; c2 = v.z; c3 = v.w;
    } else {
        if (base + 0 < n) c0 = counts[base + 0];
        if (base + 1 < n) c1 = counts[base + 1];
        if (base + 2 < n) c2 = counts[base + 2];
        if (base + 3 < n) c3 = counts[base + 3];
    }
    int s = c0 + c1 + c2 + c3;
    lds[tid] = s;
    __syncthreads();
    for (int off = 1; off < 256; off <<= 1) {
        int v = (tid >= off) ? lds[tid - off] : 0;
        __syncthreads();
        lds[tid] += v;
        __syncthreads();
    }
    int incl = lds[tid];
    int ex = incl - s;
    if (tid == 255) bsum[blockIdx.x] = incl;
    if (base + 0 < n) excl[base + 0] = ex;
    if (base + 1 < n) excl[base + 1] = ex + c0;
    if (base + 2 < n) excl[base + 2] = ex + c0 + c1;
    if (base + 3 < n) excl[base + 3] = ex + c0 + c1 + c2;
}

__global__ __launch_bounds__(64) void scan2_kernel(int* __restrict__ bsum, int nb)
{
    int lane = threadIdx.x;
    int v = (lane < nb) ? bsum[lane] : 0;
    int orig = v;
    for (int off = 1; off < 64; off <<= 1) {
        int t = __shfl_up(v, off);
        if (lane >= off) v += t;
    }
    if (lane < nb) bsum[lane] = v - orig;
}

__global__ __launch_bounds__(256) void scan3_kernel(
    const int* __restrict__ excl, const int* __restrict__ bsum,
    int* __restrict__ rp, int n, int n_edges)
{
    int i = blockIdx.x * 256 + threadIdx.x;
    if (i < n) rp[i] = excl[i] + bsum[i / SCAN_CHUNK];
    if (i == 0) rp[n] = n_edges;
}

__global__ __launch_bounds__(256) void fill2_kernel(
    const int* __restrict__ src, const int* __restrict__ dst,
    const int* __restrict__ rp, const int* __restrict__ loc,
    int* __restrict__ csr, int n_edges)
{
    int t = blockIdx.x * 256 + threadIdx.x;
    int e4 = t * 4;
    if (e4 + 4 <= n_edges) {
        int4 d = *reinterpret_cast<const int4*>(dst + e4);
        int4 s = *reinterpret_cast<const int4*>(src + e4);
        int4 l = *reinterpret_cast<const int4*>(loc + e4);
        csr[rp[d.x] + l.x] = s.x;
        csr[rp[d.y] + l.y] = s.y;
        csr[rp[d.z] + l.z] = s.z;
        csr[rp[d.w] + l.w] = s.w;
    } else {
        for (int e = e4; e < n_edges; ++e)
            csr[rp[dst[e]] + loc[e]] = src[e];
    }
}

// ------- pull (bf16): xout[v] = bf16( sum_{e:dst=v} xin[src[e]] ) ----------
// 2 nodes per wave; half-wave (32 lanes) covers one 128B bf16 row per load.
__global__ __launch_bounds__(256) void pull_bf16_kernel(
    const unsigned short* __restrict__ xin, unsigned short* __restrict__ xout,
    const int* __restrict__ rp, const int* __restrict__ csr, int n_nodes)
{
    int tid  = threadIdx.x;
    int wid  = (blockIdx.x * 256 + tid) >> 6;
    int lane = tid & 63;
    int half = lane >> 5;
    int hl   = lane & 31;
    int hb   = half << 5;
    int node = wid * 2 + half;

    int beg = 0, end = 0;
    if (node < n_nodes) { beg = rp[node]; end = rp[node + 1]; }
    int cnt  = end - beg;
    int cntO = __shfl_xor(cnt, 32);
    int maxcnt = cnt > cntO ? cnt : cntO;   // wave-uniform

    const unsigned int* xu = reinterpret_cast<const unsigned int*>(xin);
    float acc0 = 0.f, acc1 = 0.f;

    for (int base = 0; base < maxcnt; base += 32) {
        int t = base + hl;
        int idx = (t < cnt) ? csr[beg + t] : 0;     // coalesced per half-wave
        int lim = maxcnt - base; if (lim > 32) lim = 32;
        for (int i = 0; i < lim; i += 8) {
            #pragma unroll
            for (int j = 0; j < 8; ++j) {
                int s = __shfl(idx, hb + i + j);
                unsigned int u = 0u;
                if (base + i + j < cnt)
                    u = xu[(size_t)s * 32 + hl];    // 128B row per half-wave
                acc0 += __uint_as_float(u << 16);
                acc1 += __uint_as_float(u & 0xffff0000u);
            }
        }
    }

    if (node < n_nodes) {
        unsigned int o = bf16r(acc0) | (bf16r(acc1) << 16);
        reinterpret_cast<unsigned int*>(xout)[(size_t)node * 32 + hl] = o;
    }
}

// ---------------- fallback (atomic push) if ws too small -------------------
__global__ __launch_bounds__(256) void scatter_kernel(
    const float* __restrict__ xin, float* __restrict__ xout,
    const int* __restrict__ src, const int* __restrict__ dst, int n_edges)
{
    int t = blockIdx.x * blockDim.x + threadIdx.x;
    int e = t >> 4;
    if (e >= n_edges) return;
    int c = (t & 15) * 4;
    int s = src[e];
    int d = dst[e];
    const float4 v = *reinterpret_cast<const float4*>(xin + (size_t)s * D + c);
    float* o = xout + (size_t)d * D + c;
    atomicAdd(o + 0, v.x);
    atomicAdd(o + 1, v.y);
    atomicAdd(o + 2, v.z);
    atomicAdd(o + 3, v.w);
}

extern "C" void kernel_launch(void* const* d_in, const int* in_sizes, int n_in,
                              void* d_out, int out_size, void* d_ws, size_t ws_size,
                              hipStream_t stream) {
    const float* x  = (const float*)d_in[0];
    const int*   ei = (const int*)d_in[1];
    const float* W  = (const float*)d_in[2];
    const float* b  = (const float*)d_in[3];
    float* y = (float*)d_out;

    int n_nodes = in_sizes[0] / D;   // 50000
    int n_edges = in_sizes[1] / 2;   // 800000
    const int* src = ei;
    const int* dst = ei + n_edges;

    int n_pad = ((n_nodes + SCAN_CHUNK - 1) / SCAN_CHUNK) * SCAN_CHUNK; // 50176
    int nblk  = n_pad / SCAN_CHUNK;                                      // 49

    size_t bufElems = (size_t)n_nodes * D;          // 3.2M
    unsigned short* xb = (unsigned short*)d_ws;     // bf16 x
    unsigned short* Ab = xb + bufElems;             // bf16 agg ping
    unsigned short* Bb = Ab + bufElems;             // bf16 agg pong
    int* counts = (int*)(Bb + bufElems);
    int* excl   = counts + n_pad;
    int* rp     = excl + n_pad;        // n_nodes+1 used
    int* bsum   = rp + n_pad;          // 64
    int* loc    = bsum + 64;           // n_edges
    int* csr    = loc + n_edges;       // n_edges

    size_t needed = (char*)(csr + n_edges) - (char*)d_ws;

    dim3 tb(256);
    dim3 tg((n_nodes + 3) / 4);
    int e4grid = (n_edges / 4 + 255) / 256;
    int ngrid  = (n_nodes + 255) / 256;
    int n8     = (int)(bufElems / 8);
    int cgrid  = (n8 + 255) / 256;
    int pgrid  = ((n_nodes + 1) / 2 + 3) / 4;   // 2 nodes/wave, 4 waves/block

    if (needed <= ws_size) {
        // ---- bf16 copy of x + CSR build ----
        cvt_kernel<<<cgrid, tb, 0, stream>>>(x, xb, n8);
        hipMemsetAsync(counts, 0, (size_t)n_pad * sizeof(int), stream);
        hist_loc_kernel<<<e4grid, tb, 0, stream>>>(dst, counts, loc, n_edges);
        scan1_kernel<<<nblk, tb, 0, stream>>>(counts, excl, bsum, n_nodes);
        scan2_kernel<<<1, 64, 0, stream>>>(bsum, nblk);
        scan3_kernel<<<ngrid, tb, 0, stream>>>(excl, bsum, rp, n_nodes, n_edges);
        fill2_kernel<<<e4grid, tb, 0, stream>>>(src, dst, rp, loc, csr, n_edges);

        // ---- tap 0 (f32) + pull/tap chain (bf16 data, f32 accumulate) ----
        tap_kernel<<<tg, tb, 0, stream>>>(x, W, b, y, n_nodes, 1);

        pull_bf16_kernel<<<pgrid, tb, 0, stream>>>(xb, Ab, rp, csr, n_nodes);
        tap_bf16_kernel<<<tg, tb, 0, stream>>>(Ab, W + 1 * D * D, b + 1 * D, y, n_nodes);

        pull_bf16_kernel<<<pgrid, tb, 0, stream>>>(Ab, Bb, rp, csr, n_nodes);
        tap_bf16_kernel<<<tg, tb, 0, stream>>>(Bb, W + 2 * D * D, b + 2 * D, y, n_nodes);

        pull_bf16_kernel<<<pgrid, tb, 0, stream>>>(Bb, Ab, rp, csr, n_nodes);
        tap_bf16_kernel<<<tg, tb, 0, stream>>>(Ab, W + 3 * D * D, b + 3 * D, y, n_nodes);
    } else {
        // ---- fallback: atomic push path (f32) ----
        float* A = (float*)d_ws;
        float* B = A + bufElems;
        size_t bufBytes = bufElems * sizeof(float);
        int sgrid = (n_edges * 16 + 255) / 256;
        hipMemsetAsync(A, 0, bufBytes, stream);
        hipMemsetAsync(B, 0, bufBytes, stream);
        tap_kernel<<<tg, tb, 0, stream>>>(x, W, b, y, n_nodes, 1);
        scatter_kernel<<<sgrid, tb, 0, stream>>>(x, A, src, dst, n_edges);
        tap_kernel<<<tg, tb, 0, stream>>>(A, W + D * D, b + D, y, n_nodes, 0);
        scatter_kernel<<<sgrid, tb, 0, stream>>>(A, B, src, dst, n_edges);
        hipMemsetAsync(A, 0, bufBytes, stream);
        tap_kernel<<<tg, tb, 0, stream>>>(B, W + 2 * D * D, b + 2 * D, y, n_nodes, 0);
        scatter_kernel<<<sgrid, tb, 0, stream>>>(B, A, src, dst, n_edges);
        tap_kernel<<<tg, tb, 0, stream>>>(A, W + 3 * D * D, b + 3 * D, y, n_nodes, 0);
    }
}

// Round 6
// 213.900 us; speedup vs baseline: 2.1397x; 1.0993x over previous
//
#include <hip/hip_runtime.h>

#define D 64
#define SCAN_CHUNK 1024   // elements per scan1 block (256 thr x 4)

__device__ __forceinline__ unsigned int bf16r(float f) {
    unsigned int u = __float_as_uint(f);
    return (u + 0x7fffu + ((u >> 16) & 1u)) >> 16;   // RNE to bf16
}
__device__ __forceinline__ float bflo(unsigned int u) { return __uint_as_float(u << 16); }
__device__ __forceinline__ float bfhi(unsigned int u) { return __uint_as_float(u & 0xffff0000u); }

// ---------------- f32 -> bf16 row conversion (8 elems/thread) --------------
__global__ __launch_bounds__(256) void cvt_kernel(
    const float* __restrict__ in, unsigned short* __restrict__ out, int n8)
{
    int t = blockIdx.x * 256 + threadIdx.x;
    if (t >= n8) return;
    const float4* p = reinterpret_cast<const float4*>(in) + (size_t)t * 2;
    float4 v0 = p[0], v1 = p[1];
    uint4 o;
    o.x = bf16r(v0.x) | (bf16r(v0.y) << 16);
    o.y = bf16r(v0.z) | (bf16r(v0.w) << 16);
    o.z = bf16r(v1.x) | (bf16r(v1.y) << 16);
    o.w = bf16r(v1.z) | (bf16r(v1.w) << 16);
    reinterpret_cast<uint4*>(out)[t] = o;
}

// ---------------- fallback tap (f32 in) ------------------------------------
__global__ __launch_bounds__(256) void tap_kernel(
    const float* __restrict__ xin, const float* __restrict__ W,
    const float* __restrict__ b, float* __restrict__ y,
    int n_nodes, int first)
{
    __shared__ float Wt[D * (D + 1)];
    __shared__ float bs[D];
    __shared__ float xs[4][D];

    int tid = threadIdx.x;
    for (int t = tid; t < D * D; t += 256) {
        int j = t >> 6, i = t & 63;
        Wt[i * (D + 1) + j] = W[t];
    }
    if (tid < D) bs[tid] = b[tid];

    int rl = tid >> 6;
    int j  = tid & 63;
    int row = blockIdx.x * 4 + rl;
    if (row < n_nodes) xs[rl][j] = xin[(size_t)row * D + j];
    __syncthreads();

    if (row >= n_nodes) return;

    float acc = bs[j];
    #pragma unroll 8
    for (int i = 0; i < D; ++i)
        acc = fmaf(xs[rl][i], Wt[i * (D + 1) + j], acc);

    float* yp = y + (size_t)row * D + j;
    *yp = first ? acc : (*yp + acc);
}

// ------- fused 4-tap: y = sum_k Wk xk + bk (xk = x, A1, A2, A3) ------------
// 512 blocks grid-stride; all 4 transposed W's staged once per block.
__global__ __launch_bounds__(256) void tap4_kernel(
    const float* __restrict__ x,
    const unsigned short* __restrict__ A1,
    const unsigned short* __restrict__ A2,
    const unsigned short* __restrict__ A3,
    const float* __restrict__ W, const float* __restrict__ b,
    float* __restrict__ y, int n_nodes)
{
    __shared__ float Wt0[D * (D + 1)];
    __shared__ float Wt1[D * (D + 1)];
    __shared__ float Wt2[D * (D + 1)];
    __shared__ float Wt3[D * (D + 1)];
    __shared__ float bsum[D];
    __shared__ float4 xs[4][D];   // per-wave packed inputs {x,a1,a2,a3}[i]

    int tid = threadIdx.x;
    // stage W[k][j][i] -> Wtk[i*65+j]; consecutive t => i inner => stride-65
    // LDS writes (conflict-free) and coalesced global reads.
    for (int t = tid; t < D * D; t += 256) {
        int j = t >> 6, i = t & 63;
        Wt0[i * (D + 1) + j] = W[t];
        Wt1[i * (D + 1) + j] = W[D * D + t];
        Wt2[i * (D + 1) + j] = W[2 * D * D + t];
        Wt3[i * (D + 1) + j] = W[3 * D * D + t];
    }
    if (tid < D) bsum[tid] = b[tid] + b[D + tid] + b[2 * D + tid] + b[3 * D + tid];
    __syncthreads();

    int w    = tid >> 6;
    int lane = tid & 63;
    int stride = gridDim.x * 4;

    for (int r0 = blockIdx.x * 4; r0 < n_nodes; r0 += stride) {
        int row = r0 + w;
        if (row < n_nodes) {
            size_t o = (size_t)row * D + lane;
            float xv = x[o];
            float a1 = bflo((unsigned int)A1[o]);
            float a2 = bflo((unsigned int)A2[o]);
            float a3 = bflo((unsigned int)A3[o]);
            xs[w][lane] = make_float4(xv, a1, a2, a3);   // wave-private

            float acc = bsum[lane];
            #pragma unroll 16
            for (int i = 0; i < D; ++i) {
                float4 v = xs[w][i];                     // same-addr broadcast
                acc = fmaf(v.x, Wt0[i * (D + 1) + lane], acc);
                acc = fmaf(v.y, Wt1[i * (D + 1) + lane], acc);
                acc = fmaf(v.z, Wt2[i * (D + 1) + lane], acc);
                acc = fmaf(v.w, Wt3[i * (D + 1) + lane], acc);
            }
            y[o] = acc;
        }
    }
}

// ---------------- CSR build ------------------------------------------------
__global__ __launch_bounds__(256) void hist_loc_kernel(
    const int* __restrict__ dst, int* __restrict__ counts,
    int* __restrict__ loc, int n_edges)
{
    int t = blockIdx.x * 256 + threadIdx.x;
    int e4 = t * 4;
    if (e4 + 4 <= n_edges) {
        int4 d = *reinterpret_cast<const int4*>(dst + e4);
        int4 l;
        l.x = atomicAdd(&counts[d.x], 1);
        l.y = atomicAdd(&counts[d.y], 1);
        l.z = atomicAdd(&counts[d.z], 1);
        l.w = atomicAdd(&counts[d.w], 1);
        *reinterpret_cast<int4*>(loc + e4) = l;
    } else {
        for (int e = e4; e < n_edges; ++e)
            loc[e] = atomicAdd(&counts[dst[e]], 1);
    }
}

__global__ __launch_bounds__(256) void scan1_kernel(
    const int* __restrict__ counts, int* __restrict__ excl,
    int* __restrict__ bsum, int n)
{
    __shared__ int lds[256];
    int tid = threadIdx.x;
    int base = blockIdx.x * SCAN_CHUNK + tid * 4;
    int c0 = 0, c1 = 0, c2 = 0, c3 = 0;
    if (base + 3 < n) {
        int4 v = *reinterpret_cast<const int4*>(counts + base);
        c0 = v.x; c1 = v.y; c2 = v.z; c3 = v.w;
    } else {
        if (base + 0 < n) c0 = counts[base + 0];
        if (base + 1 < n) c1 = counts[base + 1];
        if (base + 2 < n) c2 = counts[base + 2];
        if (base + 3 < n) c3 = counts[base + 3];
    }
    int s = c0 + c1 + c2 + c3;
    lds[tid] = s;
    __syncthreads();
    for (int off = 1; off < 256; off <<= 1) {
        int v = (tid >= off) ? lds[tid - off] : 0;
        __syncthreads();
        lds[tid] += v;
        __syncthreads();
    }
    int incl = lds[tid];
    int ex = incl - s;
    if (tid == 255) bsum[blockIdx.x] = incl;
    if (base + 0 < n) excl[base + 0] = ex;
    if (base + 1 < n) excl[base + 1] = ex + c0;
    if (base + 2 < n) excl[base + 2] = ex + c0 + c1;
    if (base + 3 < n) excl[base + 3] = ex + c0 + c1 + c2;
}

__global__ __launch_bounds__(64) void scan2_kernel(int* __restrict__ bsum, int nb)
{
    int lane = threadIdx.x;
    int v = (lane < nb) ? bsum[lane] : 0;
    int orig = v;
    for (int off = 1; off < 64; off <<= 1) {
        int t = __shfl_up(v, off);
        if (lane >= off) v += t;
    }
    if (lane < nb) bsum[lane] = v - orig;
}

__global__ __launch_bounds__(256) void scan3_kernel(
    const int* __restrict__ excl, const int* __restrict__ bsum,
    int* __restrict__ rp, int n, int n_edges)
{
    int i = blockIdx.x * 256 + threadIdx.x;
    if (i < n) rp[i] = excl[i] + bsum[i / SCAN_CHUNK];
    if (i == 0) rp[n] = n_edges;
}

__global__ __launch_bounds__(256) void fill2_kernel(
    const int* __restrict__ src, const int* __restrict__ dst,
    const int* __restrict__ rp, const int* __restrict__ loc,
    int* __restrict__ csr, int n_edges)
{
    int t = blockIdx.x * 256 + threadIdx.x;
    int e4 = t * 4;
    if (e4 + 4 <= n_edges) {
        int4 d = *reinterpret_cast<const int4*>(dst + e4);
        int4 s = *reinterpret_cast<const int4*>(src + e4);
        int4 l = *reinterpret_cast<const int4*>(loc + e4);
        csr[rp[d.x] + l.x] = s.x;
        csr[rp[d.y] + l.y] = s.y;
        csr[rp[d.z] + l.z] = s.z;
        csr[rp[d.w] + l.w] = s.w;
    } else {
        for (int e = e4; e < n_edges; ++e)
            csr[rp[dst[e]] + loc[e]] = src[e];
    }
}

// ------- pull (bf16): xout[v] = bf16( sum_{e:dst=v} xin[src[e]] ) ----------
// 2 nodes/wave; 16-lane groups x uint2 => one vmem instr covers 4 rows.
__global__ __launch_bounds__(256) void pull_bf16_kernel(
    const unsigned short* __restrict__ xin, unsigned short* __restrict__ xout,
    const int* __restrict__ rp, const int* __restrict__ csr, int n_nodes)
{
    int tid  = threadIdx.x;
    int wid  = (blockIdx.x * 256 + tid) >> 6;
    int lane = tid & 63;
    int half = lane >> 5;        // node within wave
    int hl   = lane & 31;        // lane within half
    int hb   = half << 5;        // half base
    int g    = (lane >> 4) & 1;  // edge-group within half
    int cl   = lane & 15;        // uint2 chunk within 128B row
    int node = wid * 2 + half;

    int beg = 0, end = 0;
    if (node < n_nodes) { beg = rp[node]; end = rp[node + 1]; }
    int cnt  = end - beg;
    int cntO = __shfl_xor(cnt, 32);
    int maxcnt = cnt > cntO ? cnt : cntO;   // wave-uniform

    const uint2* xu = reinterpret_cast<const uint2*>(xin);
    float a0 = 0.f, a1 = 0.f, a2 = 0.f, a3 = 0.f;

    for (int base = 0; base < maxcnt; base += 32) {
        int t = base + hl;
        int idx = (t < cnt) ? csr[beg + t] : 0;     // coalesced per half-wave
        #pragma unroll
        for (int ii = 0; ii < 8; ++ii) {            // edges 2*ii+g = 0..15
            int el = 2 * ii + g;
            int s = __shfl(idx, hb + el);
            if (base + el < cnt) {
                uint2 u = xu[(size_t)s * 16 + cl];
                a0 += bflo(u.x); a1 += bfhi(u.x);
                a2 += bflo(u.y); a3 += bfhi(u.y);
            }
        }
        if (maxcnt - base > 16) {
            #pragma unroll
            for (int ii = 8; ii < 16; ++ii) {       // edges 16..31
                int el = 2 * ii + g;
                int s = __shfl(idx, hb + el);
                if (base + el < cnt) {
                    uint2 u = xu[(size_t)s * 16 + cl];
                    a0 += bflo(u.x); a1 += bfhi(u.x);
                    a2 += bflo(u.y); a3 += bfhi(u.y);
                }
            }
        }
    }

    // combine the two edge-groups (xor 16 swaps g0<->g1 within each half)
    a0 += __shfl_xor(a0, 16); a1 += __shfl_xor(a1, 16);
    a2 += __shfl_xor(a2, 16); a3 += __shfl_xor(a3, 16);

    if (node < n_nodes && g == 0) {
        uint2 o;
        o.x = bf16r(a0) | (bf16r(a1) << 16);
        o.y = bf16r(a2) | (bf16r(a3) << 16);
        reinterpret_cast<uint2*>(xout)[(size_t)node * 16 + cl] = o;
    }
}

// ---------------- fallback (atomic push) if ws too small -------------------
__global__ __launch_bounds__(256) void scatter_kernel(
    const float* __restrict__ xin, float* __restrict__ xout,
    const int* __restrict__ src, const int* __restrict__ dst, int n_edges)
{
    int t = blockIdx.x * blockDim.x + threadIdx.x;
    int e = t >> 4;
    if (e >= n_edges) return;
    int c = (t & 15) * 4;
    int s = src[e];
    int d = dst[e];
    const float4 v = *reinterpret_cast<const float4*>(xin + (size_t)s * D + c);
    float* o = xout + (size_t)d * D + c;
    atomicAdd(o + 0, v.x);
    atomicAdd(o + 1, v.y);
    atomicAdd(o + 2, v.z);
    atomicAdd(o + 3, v.w);
}

extern "C" void kernel_launch(void* const* d_in, const int* in_sizes, int n_in,
                              void* d_out, int out_size, void* d_ws, size_t ws_size,
                              hipStream_t stream) {
    const float* x  = (const float*)d_in[0];
    const int*   ei = (const int*)d_in[1];
    const float* W  = (const float*)d_in[2];
    const float* b  = (const float*)d_in[3];
    float* y = (float*)d_out;

    int n_nodes = in_sizes[0] / D;   // 50000
    int n_edges = in_sizes[1] / 2;   // 800000
    const int* src = ei;
    const int* dst = ei + n_edges;

    int n_pad = ((n_nodes + SCAN_CHUNK - 1) / SCAN_CHUNK) * SCAN_CHUNK; // 50176
    int nblk  = n_pad / SCAN_CHUNK;                                      // 49

    size_t bufElems = (size_t)n_nodes * D;          // 3.2M
    unsigned short* xb = (unsigned short*)d_ws;     // bf16 x
    unsigned short* Ab = xb + bufElems;             // bf16 agg1
    unsigned short* Bb = Ab + bufElems;             // bf16 agg2
    unsigned short* Cb = Bb + bufElems;             // bf16 agg3
    int* counts = (int*)(Cb + bufElems);
    int* excl   = counts + n_pad;
    int* rp     = excl + n_pad;        // n_nodes+1 used
    int* bsum   = rp + n_pad;          // 64
    int* loc    = bsum + 64;           // n_edges
    int* csr    = loc + n_edges;       // n_edges

    size_t needed = (char*)(csr + n_edges) - (char*)d_ws;

    dim3 tb(256);
    dim3 tg((n_nodes + 3) / 4);
    int e4grid = (n_edges / 4 + 255) / 256;
    int ngrid  = (n_nodes + 255) / 256;
    int n8     = (int)(bufElems / 8);
    int cgrid  = (n8 + 255) / 256;
    int pgrid  = ((n_nodes + 1) / 2 + 3) / 4;   // 2 nodes/wave, 4 waves/block

    if (needed <= ws_size) {
        // ---- bf16 copy of x + CSR build ----
        cvt_kernel<<<cgrid, tb, 0, stream>>>(x, xb, n8);
        hipMemsetAsync(counts, 0, (size_t)n_pad * sizeof(int), stream);
        hist_loc_kernel<<<e4grid, tb, 0, stream>>>(dst, counts, loc, n_edges);
        scan1_kernel<<<nblk, tb, 0, stream>>>(counts, excl, bsum, n_nodes);
        scan2_kernel<<<1, 64, 0, stream>>>(bsum, nblk);
        scan3_kernel<<<ngrid, tb, 0, stream>>>(excl, bsum, rp, n_nodes, n_edges);
        fill2_kernel<<<e4grid, tb, 0, stream>>>(src, dst, rp, loc, csr, n_edges);

        // ---- shift chain (bf16) + single fused tap ----
        pull_bf16_kernel<<<pgrid, tb, 0, stream>>>(xb, Ab, rp, csr, n_nodes);
        pull_bf16_kernel<<<pgrid, tb, 0, stream>>>(Ab, Bb, rp, csr, n_nodes);
        pull_bf16_kernel<<<pgrid, tb, 0, stream>>>(Bb, Cb, rp, csr, n_nodes);
        tap4_kernel<<<512, tb, 0, stream>>>(x, Ab, Bb, Cb, W, b, y, n_nodes);
    } else {
        // ---- fallback: atomic push path (f32) ----
        float* A = (float*)d_ws;
        float* B = A + bufElems;
        size_t bufBytes = bufElems * sizeof(float);
        int sgrid = (n_edges * 16 + 255) / 256;
        hipMemsetAsync(A, 0, bufBytes, stream);
        hipMemsetAsync(B, 0, bufBytes, stream);
        tap_kernel<<<tg, tb, 0, stream>>>(x, W, b, y, n_nodes, 1);
        scatter_kernel<<<sgrid, tb, 0, stream>>>(x, A, src, dst, n_edges);
        tap_kernel<<<tg, tb, 0, stream>>>(A, W + D * D, b + D, y, n_nodes, 0);
        scatter_kernel<<<sgrid, tb, 0, stream>>>(A, B, src, dst, n_edges);
        hipMemsetAsync(A, 0, bufBytes, stream);
        tap_kernel<<<tg, tb, 0, stream>>>(B, W + 2 * D * D, b + 2 * D, y, n_nodes, 0);
        scatter_kernel<<<sgrid, tb, 0, stream>>>(B, A, src, dst, n_edges);
        tap_kernel<<<tg, tb, 0, stream>>>(A, W + 3 * D * D, b + 3 * D, y, n_nodes, 0);
    }
}